// Round 7
// baseline (284.562 us; speedup 1.0000x reference)
//
#include <hip/hip_runtime.h>

typedef unsigned short u16;
typedef float f32x4 __attribute__((ext_vector_type(4)));
typedef short bf16x8 __attribute__((ext_vector_type(8)));

constexpr int Bn = 4, Ln = 512, Mn = 32, EMBn = 512, Hn = 8, HSn = 64;
constexpr int Rn = Mn * Hn; // 256
constexpr int NBLK = 512;
constexpr size_t BAR_OFF = 12u << 20;

__device__ __forceinline__ float wave_sum(float v) {
#pragma unroll
  for (int off = 1; off < 64; off <<= 1) v += __shfl_xor(v, off, 64);
  return v;
}
__device__ __forceinline__ u16 f2bf(float f) {
  unsigned u = __float_as_uint(f);
  unsigned r = (u + 0x7FFFu + ((u >> 16) & 1u)) >> 16;
  return (u16)r;
}
__device__ __forceinline__ unsigned pack2(float a, float b) {
  return (unsigned)f2bf(a) | ((unsigned)f2bf(b) << 16);
}

// ---------------------------------------------------------------------------
// Distributed-flag grid barrier. flags[b*32]: one 128B line per block
// (parallel stores, no RMW contention). Block 0 polls all flags (256 thr x 2
// acquire loads), publishes gen; other blocks read-poll gen (read-shared).
// Generations are monotone 1,2,3 per launch; flags memset to 0 pre-launch.
// ---------------------------------------------------------------------------
__device__ __forceinline__ void gbar(unsigned* flags, unsigned* gen,
                                     unsigned g, int bid, int tid) {
  __syncthreads();
  if (tid == 0) {
    __threadfence();
    __hip_atomic_store(&flags[(unsigned)bid * 32], g, __ATOMIC_RELEASE,
                       __HIP_MEMORY_SCOPE_AGENT);
  }
  if (bid == 0) {
    unsigned i0 = (unsigned)tid * 2;
    unsigned f;
    do {
      f = __hip_atomic_load(&flags[i0 * 32], __ATOMIC_ACQUIRE,
                            __HIP_MEMORY_SCOPE_AGENT);
    } while (f < g);
    do {
      f = __hip_atomic_load(&flags[(i0 + 1) * 32], __ATOMIC_ACQUIRE,
                            __HIP_MEMORY_SCOPE_AGENT);
    } while (f < g);
    __syncthreads();
    if (tid == 0)
      __hip_atomic_store(gen, g, __ATOMIC_RELEASE, __HIP_MEMORY_SCOPE_AGENT);
  } else {
    if (tid == 0) {
      unsigned gg;
      do {
        __builtin_amdgcn_s_sleep(1);
        gg = __hip_atomic_load(gen, __ATOMIC_ACQUIRE,
                               __HIP_MEMORY_SCOPE_AGENT);
      } while (gg < g);
      __threadfence();
    }
    __syncthreads();
  }
}

// ---------------------------------------------------------------------------
// MFMA GEMM core: C tile 32x64 = A[32xK] * B^T[64xK], K=512, strides 512.
// LDS-staged, double-buffered, XOR-swizzled. 256 threads. (proven R2/R3)
// ---------------------------------------------------------------------------
template <bool BIAS>
__device__ __forceinline__ void gemm_core(const u16* __restrict__ Ag,
                                          const u16* __restrict__ Bg,
                                          float* __restrict__ Cg,
                                          const float* __restrict__ pbv,
                                          int r0, int n0, int tid,
                                          u16* smem) {
  const int wave = tid >> 6, lane = tid & 63;
  const int srow = lane >> 3, sblk = lane & 7;
  const u16* gsrc0;
  const u16* gsrc1;
  const u16* gsrc2;
  unsigned lofs0, lofs1, lofs2, lstep0, lstep1, lstep2;
  {
    int id0 = wave * 3;
#pragma unroll
    for (int q = 0; q < 3; ++q) {
      int id = id0 + q;
      const u16* g;
      unsigned lo, ls;
      if (id < 4) {
        int row = id * 8 + srow;
        g = Ag + (size_t)(r0 + row) * 512 + sblk * 8;
        lo = row * 64 + (((sblk * 16) ^ ((row & 7) << 4)) >> 1);
        ls = 2048;
      } else {
        int row = (id - 4) * 8 + srow;
        g = Bg + (size_t)(n0 + row) * 512 + sblk * 8;
        lo = 4096 + row * 64 + (((sblk * 16) ^ ((row & 7) << 4)) >> 1);
        ls = 4096;
      }
      if (q == 0) { gsrc0 = g; lofs0 = lo; lstep0 = ls; }
      else if (q == 1) { gsrc1 = g; lofs1 = lo; lstep1 = ls; }
      else { gsrc2 = g; lofs2 = lo; lstep2 = ls; }
    }
  }
  uint4 rv0 = *(const uint4*)gsrc0;
  uint4 rv1 = *(const uint4*)gsrc1;
  uint4 rv2 = *(const uint4*)gsrc2;
  *(uint4*)&smem[lofs0] = rv0;
  *(uint4*)&smem[lofs1] = rv1;
  *(uint4*)&smem[lofs2] = rv2;
  __syncthreads();

  f32x4 acc0 = {0.f, 0.f, 0.f, 0.f};
  f32x4 acc1 = {0.f, 0.f, 0.f, 0.f};
  const int ra = (wave >> 1) * 16 + (lane & 15);
  const int nb = (wave & 1) * 32 + (lane & 15);
  const unsigned asw = (unsigned)((ra & 7) << 4);
  const unsigned bsw = (unsigned)((nb & 7) << 4);
  const unsigned kg = (unsigned)((lane >> 4) * 16);

#pragma unroll
  for (int c = 0; c < 8; ++c) {
    const int cur = c & 1;
    if (c < 7) {
      rv0 = *(const uint4*)(gsrc0 + (c + 1) * 64);
      rv1 = *(const uint4*)(gsrc1 + (c + 1) * 64);
      rv2 = *(const uint4*)(gsrc2 + (c + 1) * 64);
    }
    const char* Ab = (const char*)(smem + cur * 2048);
    const char* Bb = (const char*)(smem + 4096 + cur * 4096);
#pragma unroll
    for (int ks = 0; ks < 2; ++ks) {
      unsigned kb = ks * 64 + kg;
      bf16x8 a = *(const bf16x8*)(Ab + ra * 128 + (kb ^ asw));
      bf16x8 b0 = *(const bf16x8*)(Bb + nb * 128 + (kb ^ bsw));
      bf16x8 b1 = *(const bf16x8*)(Bb + (nb + 16) * 128 + (kb ^ bsw));
      acc0 = __builtin_amdgcn_mfma_f32_16x16x32_bf16(a, b0, acc0, 0, 0, 0);
      acc1 = __builtin_amdgcn_mfma_f32_16x16x32_bf16(a, b1, acc1, 0, 0, 0);
    }
    if (c < 7) {
      unsigned bo = (unsigned)(cur ^ 1);
      *(uint4*)&smem[lofs0 + bo * lstep0] = rv0;
      *(uint4*)&smem[lofs1 + bo * lstep1] = rv1;
      *(uint4*)&smem[lofs2 + bo * lstep2] = rv2;
    }
    __syncthreads();
  }

  const int rg = r0 + (wave >> 1) * 16 + ((lane >> 4) << 2);
  const int cg = n0 + (wave & 1) * 32 + (lane & 15);
#pragma unroll
  for (int j = 0; j < 4; ++j) {
    float v0 = acc0[j], v1 = acc1[j];
    if (BIAS) {
      float pv = pbv[rg + j];
      v0 = (v0 + pv) * 0.125f;
      v1 = (v1 + pv) * 0.125f;
    }
    Cg[(size_t)(rg + j) * 512 + cg] = v0;
    Cg[(size_t)(rg + j) * 512 + cg + 16] = v1;
  }
}

// ---------------------------------------------------------------------------
// Persistent cooperative kernel, 512 blocks x 256 threads:
// A) LN + P-proj | bar1 | B) score GEMM + h-transpose | bar2 |
// C) fused softmax + gmat | bar3 | E) out reduction.
// ---------------------------------------------------------------------------
__global__ __launch_bounds__(256, 2) void persist_kernel(
    const float* __restrict__ x, const float* __restrict__ gam,
    const float* __restrict__ bet, const float* __restrict__ cells,
    const float* __restrict__ q_w, const float* __restrict__ q_b,
    const float* __restrict__ v, const float* __restrict__ vbp,
    u16* __restrict__ hb, u16* __restrict__ htb, u16* __restrict__ Pb,
    float* __restrict__ pb, float* __restrict__ S, float* __restrict__ G,
    float* __restrict__ out, unsigned* __restrict__ bar) {
  __shared__ __align__(16) char SMEM[32768];
  const int bid = blockIdx.x, tid = threadIdx.x;
  const int wid = tid >> 6, lane = tid & 63;
  unsigned* flags = bar;
  unsigned* gen = bar + NBLK * 32;

  // ---------------- Phase A: LN (vblk 0..511) + P projection (512..767)
  for (int vblk = bid; vblk < 768; vblk += 512) {
    if (vblk < 512) {
      int row = vblk * 4 + wid;
      const float* xr = x + (size_t)row * EMBn + lane * 8;
      float4 a0 = *(const float4*)xr;
      float4 a1 = *(const float4*)(xr + 4);
      float s = a0.x + a0.y + a0.z + a0.w + a1.x + a1.y + a1.z + a1.w;
      float ss = a0.x * a0.x + a0.y * a0.y + a0.z * a0.z + a0.w * a0.w +
                 a1.x * a1.x + a1.y * a1.y + a1.z * a1.z + a1.w * a1.w;
      s = wave_sum(s);
      ss = wave_sum(ss);
      float mu = s * (1.0f / EMBn);
      float var = ss * (1.0f / EMBn) - mu * mu;
      float rstd = rsqrtf(var + 1e-5f);
      const float* gp = gam + lane * 8;
      const float* bp = bet + lane * 8;
      float4 g0 = *(const float4*)gp, g1 = *(const float4*)(gp + 4);
      float4 b0 = *(const float4*)bp, b1 = *(const float4*)(bp + 4);
      float4 o0, o1;
      o0.x = (a0.x - mu) * rstd * g0.x + b0.x;
      o0.y = (a0.y - mu) * rstd * g0.y + b0.y;
      o0.z = (a0.z - mu) * rstd * g0.z + b0.z;
      o0.w = (a0.w - mu) * rstd * g0.w + b0.w;
      o1.x = (a1.x - mu) * rstd * g1.x + b1.x;
      o1.y = (a1.y - mu) * rstd * g1.y + b1.y;
      o1.z = (a1.z - mu) * rstd * g1.z + b1.z;
      o1.w = (a1.w - mu) * rstd * g1.w + b1.w;
      uint4 st;
      st.x = pack2(o0.x, o0.y);
      st.y = pack2(o0.z, o0.w);
      st.z = pack2(o1.x, o1.y);
      st.w = pack2(o1.z, o1.w);
      *(uint4*)&hb[(size_t)row * EMBn + lane * 8] = st;
    } else {
      int r = vblk - 512;
      int hh = r & 7;
      float* cs = (float*)SMEM;
      if (tid < HSn) cs[tid] = cells[(size_t)r * HSn + tid];
      __syncthreads();
      for (int e = tid; e < EMBn; e += 256) {
        float acc = 0.f;
#pragma unroll 8
        for (int s2 = 0; s2 < HSn; ++s2)
          acc += cs[s2] * q_w[(size_t)(hh * HSn + s2) * EMBn + e];
        Pb[(size_t)r * EMBn + e] = f2bf(acc);
      }
      if (tid == 0) {
        float a = 0.f;
        for (int s2 = 0; s2 < HSn; ++s2) a += cs[s2] * q_b[hh * HSn + s2];
        pb[r] = a;
      }
      __syncthreads();
    }
  }
  gbar(flags, gen, 1u, bid, tid);

  // ---------------- Phase B: score GEMM (bid<256) + transpose (bid>=256)
  if (bid < 256) {
    int b = bid >> 6, rem = bid & 63;
    int r0 = (rem >> 3) * 32, l0 = (rem & 7) * 64;
    gemm_core<true>(Pb, hb + (size_t)b * Ln * EMBn, S + (size_t)b * Rn * Ln,
                    pb, r0, l0, tid, (u16*)SMEM);
  } else {
    int t = bid - 256;
    int b = t >> 6, rem = t & 63;
    int l0 = (rem >> 3) * 64, j0 = (rem & 7) * 64;
    u16(*ts)[65] = (u16(*)[65])SMEM;
#pragma unroll
    for (int i = 0; i < 4; ++i) {
      int idx = tid + i * 256;
      int row = idx >> 4, c4 = (idx & 15) * 4;
      uint2 u = *(const uint2*)&hb[(size_t)(b * Ln + l0 + row) * EMBn + j0 + c4];
      ts[row][c4] = (u16)(u.x & 0xffffu);
      ts[row][c4 + 1] = (u16)(u.x >> 16);
      ts[row][c4 + 2] = (u16)(u.y & 0xffffu);
      ts[row][c4 + 3] = (u16)(u.y >> 16);
    }
    __syncthreads();
#pragma unroll
    for (int i = 0; i < 4; ++i) {
      int idx = tid + i * 256;
      int jr = idx >> 4, lc4 = (idx & 15) * 4;
      unsigned lo = (unsigned)ts[lc4][jr] | ((unsigned)ts[lc4 + 1][jr] << 16);
      unsigned hi = (unsigned)ts[lc4 + 2][jr] | ((unsigned)ts[lc4 + 3][jr] << 16);
      uint2 u;
      u.x = lo;
      u.y = hi;
      *(uint2*)&htb[(size_t)(b * EMBn + j0 + jr) * Ln + l0 + lc4] = u;
    }
  }
  gbar(flags, gen, 2u, bid, tid);

  // ---------------- Phase C: fused softmax + gmat, 16-row groups.
  {
    int b = bid >> 7, rem = bid & 127;
    int r0 = (rem >> 3) * 16, j0 = (rem & 7) * 64;
    u16* Wlds = (u16*)SMEM;          // [16][512] bf16 swizzled, 16 KiB
    char* Bl = SMEM + 16384;         // 2 x [64][64] bf16 swizzled, 16 KiB
    {
      int row = tid >> 4, sub = tid & 15;
      const float* sp = S + ((size_t)b * Rn + r0 + row) * Ln + sub * 32;
      float4 vv[8];
#pragma unroll
      for (int i = 0; i < 8; ++i) vv[i] = *(const float4*)(sp + i * 4);
      float mx = -1e30f;
#pragma unroll
      for (int i = 0; i < 8; ++i)
        mx = fmaxf(mx, fmaxf(fmaxf(vv[i].x, vv[i].y), fmaxf(vv[i].z, vv[i].w)));
#pragma unroll
      for (int off = 1; off < 16; off <<= 1)
        mx = fmaxf(mx, __shfl_xor(mx, off, 64));
      float sum = 0.f;
#pragma unroll
      for (int i = 0; i < 8; ++i) {
        vv[i].x = __expf(vv[i].x - mx);
        vv[i].y = __expf(vv[i].y - mx);
        vv[i].z = __expf(vv[i].z - mx);
        vv[i].w = __expf(vv[i].w - mx);
        sum += vv[i].x + vv[i].y + vv[i].z + vv[i].w;
      }
#pragma unroll
      for (int off = 1; off < 16; off <<= 1) sum += __shfl_xor(sum, off, 64);
      float inv = 1.0f / sum;
      unsigned swz = (unsigned)((row & 7) << 4);
      char* wbase = (char*)Wlds + row * 1024;
#pragma unroll
      for (int q = 0; q < 4; ++q) {
        uint4 st;
        st.x = pack2(vv[2 * q].x * inv, vv[2 * q].y * inv);
        st.y = pack2(vv[2 * q].z * inv, vv[2 * q].w * inv);
        st.z = pack2(vv[2 * q + 1].x * inv, vv[2 * q + 1].y * inv);
        st.w = pack2(vv[2 * q + 1].z * inv, vv[2 * q + 1].w * inv);
        *(uint4*)(wbase + (((unsigned)(sub * 64 + q * 16)) ^ swz)) = st;
      }
    }
    int brow = tid >> 2, bks = (tid & 3) * 2;
    const u16* bg = htb + ((size_t)b * EMBn + j0 + brow) * Ln + bks * 8;
    unsigned bswz = (unsigned)((brow & 7) << 4);
    unsigned bofs0 = brow * 128 + (((unsigned)(bks * 16)) ^ bswz);
    unsigned bofs1 = brow * 128 + (((unsigned)(bks * 16 + 16)) ^ bswz);
    uint4 rv0 = *(const uint4*)bg;
    uint4 rv1 = *(const uint4*)(bg + 8);
    *(uint4*)(Bl + bofs0) = rv0;
    *(uint4*)(Bl + bofs1) = rv1;
    __syncthreads();

    const int wave = tid >> 6;
    const int lr = lane & 15;
    const unsigned lg = (unsigned)(lane >> 4);
    f32x4 acc = {0.f, 0.f, 0.f, 0.f};
    const unsigned asw = (unsigned)((lr & 7) << 4);
    const int jloc = wave * 16 + lr;
    const unsigned bsw2 = (unsigned)((jloc & 7) << 4);
    const char* Abase = (const char*)Wlds + lr * 1024;
#pragma unroll
    for (int c = 0; c < 8; ++c) {
      const int cur = c & 1;
      if (c < 7) {
        rv0 = *(const uint4*)(bg + (c + 1) * 64);
        rv1 = *(const uint4*)(bg + (c + 1) * 64 + 8);
      }
      const char* Bb = Bl + cur * 8192;
#pragma unroll
      for (int ks = 0; ks < 2; ++ks) {
        unsigned kbA = (unsigned)(c * 128 + ks * 64) + lg * 16;
        unsigned kbB = (unsigned)(ks * 64) + lg * 16;
        bf16x8 a = *(const bf16x8*)(Abase + (kbA ^ asw));
        bf16x8 bb = *(const bf16x8*)(Bb + jloc * 128 + (kbB ^ bsw2));
        acc = __builtin_amdgcn_mfma_f32_16x16x32_bf16(a, bb, acc, 0, 0, 0);
      }
      if (c < 7) {
        char* Bo = Bl + (cur ^ 1) * 8192;
        *(uint4*)(Bo + bofs0) = rv0;
        *(uint4*)(Bo + bofs1) = rv1;
      }
      __syncthreads();
    }
    const int rg = r0 + (int)lg * 4;
    const int cg = j0 + jloc;
#pragma unroll
    for (int i = 0; i < 4; ++i) {
      G[((size_t)b * Rn + rg + i) * EMBn + cg] = acc[i];
    }
  }
  gbar(flags, gen, 3u, bid, tid);

  // ---------------- Phase E: out (1024 units, 2 per block)
  float(*Gs)[EMBn] = (float(*)[EMBn])SMEM; // 8 KiB
#pragma unroll
  for (int it = 0; it < 2; ++it) {
    if (it) __syncthreads();
    int vblk = bid + it * 512;
    int sc = vblk & 3, hh = (vblk >> 2) & 7, m = vblk >> 5;
    int r = m * Hn + hh;
#pragma unroll
    for (int i = 0; i < 2; ++i) {
      int idx4 = tid + i * 256;
      int bb = idx4 >> 7, e4 = (idx4 & 127) << 2;
      *(float4*)&Gs[bb][e4] =
          *(const float4*)&G[((size_t)bb * Rn + r) * EMBn + e4];
    }
    __syncthreads();
#pragma unroll
    for (int i = 0; i < 4; ++i) {
      int rr = sc * 16 + wid * 4 + i;
      const float* vr =
          v + ((size_t)m * EMBn + hh * HSn + rr) * EMBn + lane * 8;
      float4 v0 = *(const float4*)vr;
      float4 v1 = *(const float4*)(vr + 4);
      float acc[Bn];
#pragma unroll
      for (int bb = 0; bb < Bn; ++bb) {
        const float* gp = &Gs[bb][lane * 8];
        float4 g0 = *(const float4*)gp;
        float4 g1 = *(const float4*)(gp + 4);
        acc[bb] = v0.x * g0.x + v0.y * g0.y + v0.z * g0.z + v0.w * g0.w +
                  v1.x * g1.x + v1.y * g1.y + v1.z * g1.z + v1.w * g1.w;
      }
#pragma unroll
      for (int off = 1; off < 64; off <<= 1) {
#pragma unroll
        for (int bb = 0; bb < Bn; ++bb) acc[bb] += __shfl_xor(acc[bb], off, 64);
      }
      if (lane == 0) {
        float vbv = vbp[(size_t)m * EMBn + hh * HSn + rr];
#pragma unroll
        for (int bb = 0; bb < Bn; ++bb) {
          out[(((size_t)bb * Hn + hh) * Mn + m) * HSn + rr] = acc[bb] + vbv;
        }
      }
    }
  }
}

extern "C" void kernel_launch(void* const* d_in, const int* in_sizes, int n_in,
                              void* d_out, int out_size, void* d_ws,
                              size_t ws_size, hipStream_t stream) {
  const float* x = (const float*)d_in[0];
  const float* cells = (const float*)d_in[1];
  const float* q_w = (const float*)d_in[2];
  const float* q_b = (const float*)d_in[3];
  const float* v = (const float*)d_in[4];
  const float* vbp = (const float*)d_in[5];
  const float* ln_g = (const float*)d_in[6];
  const float* ln_b = (const float*)d_in[7];
  float* out = (float*)d_out;

  u16* hb = (u16*)d_ws;                             // 2 MB
  u16* htb = hb + (size_t)Bn * Ln * EMBn;           // 2 MB
  u16* Pb = htb + (size_t)Bn * Ln * EMBn;           // 256 KB
  float* pb = (float*)(Pb + (size_t)Rn * EMBn);     // 1 KB
  float* S = pb + Rn;                               // 2 MB
  float* G = S + (size_t)Bn * Rn * Ln;              // 2 MB
  unsigned* bar = (unsigned*)((char*)d_ws + BAR_OFF);

  // flags: 512 * 128B + gen line
  hipMemsetAsync(bar, 0, NBLK * 128 + 128, stream);

  void* args[] = {&x,   &ln_g, &ln_b, &cells, &q_w, &q_b, &v,   &vbp,
                  &hb,  &htb,  &Pb,   &pb,    &S,   &G,   &out, &bar};
  hipLaunchCooperativeKernel((const void*)persist_kernel, dim3(NBLK),
                             dim3(256), args, 0, stream);
}

// Round 8
// 39.537 us; speedup vs baseline: 7.1973x; 7.1973x over previous
//
#include <hip/hip_runtime.h>

typedef unsigned short u16;
typedef float f32x4 __attribute__((ext_vector_type(4)));
typedef short bf16x8 __attribute__((ext_vector_type(8)));

constexpr int Bn = 4, Ln = 512, Mn = 32, EMBn = 512, Hn = 8, HSn = 64;
constexpr int Rn = Mn * Hn; // 256

__device__ __forceinline__ float wave_sum(float v) {
#pragma unroll
  for (int off = 1; off < 64; off <<= 1) v += __shfl_xor(v, off, 64);
  return v;
}
__device__ __forceinline__ u16 f2bf(float f) {
  unsigned u = __float_as_uint(f);
  unsigned r = (u + 0x7FFFu + ((u >> 16) & 1u)) >> 16;
  return (u16)r;
}
__device__ __forceinline__ unsigned pack2(float a, float b) {
  return (unsigned)f2bf(a) | ((unsigned)f2bf(b) << 16);
}

// ---------------------------------------------------------------------------
// K1: blocks [0,512): LayerNorm -> h_bf16. blocks [512,768): P = cells*q_w.
// (verbatim from R3; htb removed)
// ---------------------------------------------------------------------------
__global__ __launch_bounds__(256) void ln_pproj_kernel(
    const float* __restrict__ x, const float* __restrict__ gam,
    const float* __restrict__ bet, const float* __restrict__ cells,
    const float* __restrict__ q_w, const float* __restrict__ q_b,
    u16* __restrict__ hb, u16* __restrict__ Pb, float* __restrict__ pb) {
  int bid = blockIdx.x, tid = threadIdx.x;
  __shared__ float cs[HSn];
  if (bid < 512) {
    int row = bid * 4 + (tid >> 6), lane = tid & 63;
    const float* xr = x + (size_t)row * EMBn + lane * 8;
    float4 a0 = *(const float4*)xr;
    float4 a1 = *(const float4*)(xr + 4);
    float s = a0.x + a0.y + a0.z + a0.w + a1.x + a1.y + a1.z + a1.w;
    float ss = a0.x * a0.x + a0.y * a0.y + a0.z * a0.z + a0.w * a0.w +
               a1.x * a1.x + a1.y * a1.y + a1.z * a1.z + a1.w * a1.w;
    s = wave_sum(s);
    ss = wave_sum(ss);
    float mu = s * (1.0f / EMBn);
    float var = ss * (1.0f / EMBn) - mu * mu;
    float rstd = rsqrtf(var + 1e-5f);
    const float* gp = gam + lane * 8;
    const float* bp = bet + lane * 8;
    float4 g0 = *(const float4*)gp, g1 = *(const float4*)(gp + 4);
    float4 b0 = *(const float4*)bp, b1 = *(const float4*)(bp + 4);
    float4 o0, o1;
    o0.x = (a0.x - mu) * rstd * g0.x + b0.x;
    o0.y = (a0.y - mu) * rstd * g0.y + b0.y;
    o0.z = (a0.z - mu) * rstd * g0.z + b0.z;
    o0.w = (a0.w - mu) * rstd * g0.w + b0.w;
    o1.x = (a1.x - mu) * rstd * g1.x + b1.x;
    o1.y = (a1.y - mu) * rstd * g1.y + b1.y;
    o1.z = (a1.z - mu) * rstd * g1.z + b1.z;
    o1.w = (a1.w - mu) * rstd * g1.w + b1.w;
    uint4 st;
    st.x = pack2(o0.x, o0.y);
    st.y = pack2(o0.z, o0.w);
    st.z = pack2(o1.x, o1.y);
    st.w = pack2(o1.z, o1.w);
    *(uint4*)&hb[(size_t)row * EMBn + lane * 8] = st;
  } else {
    int r = bid - 512;
    int hh = r & 7;
    if (tid < HSn) cs[tid] = cells[(size_t)r * HSn + tid];
    __syncthreads();
    for (int e = tid; e < EMBn; e += 256) {
      float acc = 0.f;
#pragma unroll 8
      for (int s2 = 0; s2 < HSn; ++s2)
        acc += cs[s2] * q_w[(size_t)(hh * HSn + s2) * EMBn + e];
      Pb[(size_t)r * EMBn + e] = f2bf(acc);
    }
    if (tid == 0) {
      float a = 0.f;
      for (int s2 = 0; s2 < HSn; ++s2) a += cs[s2] * q_b[hh * HSn + s2];
      pb[r] = a;
    }
  }
}

// ---------------------------------------------------------------------------
// K2: fused score + softmax + gmat. Block = (b, 16-row r-group, j-half).
// Grid 128, 512 threads (8 waves).
// Phase 1: S[16][512] = (P . h^T + pb)*0.125 -- A=P in shared LDS, B=h rows
//   wave-private staged (wave w owns l-strip w*64..+64), reg-prefetched.
// Softmax in-fragment, cross-wave stats in LDS; W -> W_lds (bf16, swizzled).
// Phase 2: G[16][256] = W . h  -- A=W_lds, B via transpose-on-write staging.
// ---------------------------------------------------------------------------
__global__ __launch_bounds__(512) void fused_kernel(
    const u16* __restrict__ hb, const u16* __restrict__ Pb,
    const float* __restrict__ pb, float* __restrict__ G) {
  __shared__ __align__(16) char SM[99328];
  char* P_lds = SM;            // 16 KB  [16 r][512 e] bf16, XOR (r&7)<<4
  char* W_lds = SM + 16384;    // 16 KB  [16 r][512 l] bf16, XOR (r&7)<<4
  float* smax = (float*)(SM + 32768);  // [16][8]
  float* ssum = smax + 128;            // [16][8]
  char* tiles = SM + 33792;    // per-wave staging: p1 8 KB, p2 4 KB

  const int bid = blockIdx.x, tid = threadIdx.x;
  const int b = bid >> 5, rg = (bid >> 1) & 15, jh = bid & 1;
  const int r0 = rg * 16, j0 = jh * 256;
  const int w = tid >> 6, lane = tid & 63;
  const int g = lane >> 4, n = lane & 15;

  // ---- load P tile into LDS
  {
    int r = tid >> 5;
    int ecb = (tid & 31) * 32;  // byte offset in 1024-B row
    const u16* src = Pb + (size_t)(r0 + r) * 512 + (ecb >> 1);
    uint4 v0 = *(const uint4*)src;
    uint4 v1 = *(const uint4*)(src + 8);
    unsigned sw = (unsigned)((r & 7) << 4);
    *(uint4*)(P_lds + r * 1024 + (ecb ^ sw)) = v0;
    *(uint4*)(P_lds + r * 1024 + ((ecb + 16) ^ sw)) = v1;
  }
  __syncthreads();

  // ---- Phase 1: per-wave l-strip GEMM, no block barriers
  char* T1 = tiles + w * 8192;  // [64 l][64 e] bf16, XOR (l&7)<<4
  const int srow = lane >> 3, scol = lane & 7;
  const u16* hbase =
      hb + ((size_t)(b * 512 + w * 64 + srow)) * 512 + scol * 8;
  uint4 pf[8];
#pragma unroll
  for (int u = 0; u < 8; ++u) pf[u] = *(const uint4*)(hbase + u * 4096);

  f32x4 acc0 = {0, 0, 0, 0}, acc1 = {0, 0, 0, 0};
  f32x4 acc2 = {0, 0, 0, 0}, acc3 = {0, 0, 0, 0};
  const unsigned asw = (unsigned)((n & 7) << 4);

#pragma unroll
  for (int c = 0; c < 8; ++c) {
#pragma unroll
    for (int u = 0; u < 8; ++u) {
      int l = u * 8 + srow;
      *(uint4*)(T1 + l * 128 + ((scol * 16) ^ ((l & 7) << 4))) = pf[u];
    }
    if (c < 7) {
#pragma unroll
      for (int u = 0; u < 8; ++u)
        pf[u] = *(const uint4*)(hbase + u * 4096 + (c + 1) * 64);
    }
#pragma unroll
    for (int kk = 0; kk < 2; ++kk) {
      int kb = c * 128 + kk * 64 + g * 16;
      bf16x8 a = *(const bf16x8*)(P_lds + n * 1024 + (kb ^ asw));
      int kb2 = kk * 64 + g * 16;
      bf16x8 b0 = *(const bf16x8*)(T1 + (0 * 16 + n) * 128 +
                                   (kb2 ^ ((n & 7) << 4)));
      bf16x8 b1 = *(const bf16x8*)(T1 + (1 * 16 + n) * 128 +
                                   (kb2 ^ ((n & 7) << 4)));
      bf16x8 b2 = *(const bf16x8*)(T1 + (2 * 16 + n) * 128 +
                                   (kb2 ^ ((n & 7) << 4)));
      bf16x8 b3 = *(const bf16x8*)(T1 + (3 * 16 + n) * 128 +
                                   (kb2 ^ ((n & 7) << 4)));
      acc0 = __builtin_amdgcn_mfma_f32_16x16x32_bf16(a, b0, acc0, 0, 0, 0);
      acc1 = __builtin_amdgcn_mfma_f32_16x16x32_bf16(a, b1, acc1, 0, 0, 0);
      acc2 = __builtin_amdgcn_mfma_f32_16x16x32_bf16(a, b2, acc2, 0, 0, 0);
      acc3 = __builtin_amdgcn_mfma_f32_16x16x32_bf16(a, b3, acc3, 0, 0, 0);
    }
  }

  // ---- softmax: lane holds C[r=g*4+i][l = w*64 + nt*16 + n]
  float sv[4][4];
  float pbv[4];
#pragma unroll
  for (int i = 0; i < 4; ++i) pbv[i] = pb[r0 + g * 4 + i];
#pragma unroll
  for (int i = 0; i < 4; ++i) {
    sv[0][i] = (acc0[i] + pbv[i]) * 0.125f;
    sv[1][i] = (acc1[i] + pbv[i]) * 0.125f;
    sv[2][i] = (acc2[i] + pbv[i]) * 0.125f;
    sv[3][i] = (acc3[i] + pbv[i]) * 0.125f;
  }
  float mx[4];
#pragma unroll
  for (int i = 0; i < 4; ++i) {
    mx[i] = fmaxf(fmaxf(sv[0][i], sv[1][i]), fmaxf(sv[2][i], sv[3][i]));
#pragma unroll
    for (int off = 1; off < 16; off <<= 1)
      mx[i] = fmaxf(mx[i], __shfl_xor(mx[i], off, 64));
  }
  if (n == 0) {
#pragma unroll
    for (int i = 0; i < 4; ++i) smax[(g * 4 + i) * 8 + w] = mx[i];
  }
  __syncthreads();
  float gm[4];
#pragma unroll
  for (int i = 0; i < 4; ++i) {
    float m = smax[(g * 4 + i) * 8];
#pragma unroll
    for (int ww = 1; ww < 8; ++ww)
      m = fmaxf(m, smax[(g * 4 + i) * 8 + ww]);
    gm[i] = m;
  }
  float e[4][4];
  float sum[4];
#pragma unroll
  for (int i = 0; i < 4; ++i) {
    e[0][i] = __expf(sv[0][i] - gm[i]);
    e[1][i] = __expf(sv[1][i] - gm[i]);
    e[2][i] = __expf(sv[2][i] - gm[i]);
    e[3][i] = __expf(sv[3][i] - gm[i]);
    sum[i] = e[0][i] + e[1][i] + e[2][i] + e[3][i];
#pragma unroll
    for (int off = 1; off < 16; off <<= 1)
      sum[i] += __shfl_xor(sum[i], off, 64);
  }
  if (n == 0) {
#pragma unroll
    for (int i = 0; i < 4; ++i) ssum[(g * 4 + i) * 8 + w] = sum[i];
  }
  __syncthreads();
  float inv[4];
#pragma unroll
  for (int i = 0; i < 4; ++i) {
    float t = ssum[(g * 4 + i) * 8];
#pragma unroll
    for (int ww = 1; ww < 8; ++ww) t += ssum[(g * 4 + i) * 8 + ww];
    inv[i] = 1.0f / t;
  }
  // write W to LDS [16 r][512 l] swizzled
#pragma unroll
  for (int nt = 0; nt < 4; ++nt) {
#pragma unroll
    for (int i = 0; i < 4; ++i) {
      int r = g * 4 + i;
      int l = w * 64 + nt * 16 + n;
      *(u16*)(W_lds + r * 1024 + ((l * 2) ^ ((r & 7) << 4))) =
          f2bf(e[nt][i] * inv[i]);
    }
  }
  __syncthreads();

  // ---- Phase 2: G[16 r][32 j per wave] = W . h ; B staged transpose-on-write
  char* T2 = tiles + w * 4096;  // [32 j][64 l] bf16, swz2
  const int jw0 = j0 + w * 32;
  const int srow2 = lane >> 2, sj = (lane & 3) * 8;
  const u16* h2base = hb + ((size_t)(b * 512 + srow2)) * 512 + jw0 + sj;
  uint4 pf2[4];
#pragma unroll
  for (int u = 0; u < 4; ++u)
    pf2[u] = *(const uint4*)(h2base + (size_t)(u * 16) * 512);

  f32x4 ac20 = {0, 0, 0, 0}, ac21 = {0, 0, 0, 0};
#pragma unroll
  for (int c = 0; c < 8; ++c) {
#pragma unroll
    for (int u = 0; u < 4; ++u) {
      int lc = u * 16 + srow2;  // local l in chunk
      const u16* pv = (const u16*)&pf2[u];
#pragma unroll
      for (int k = 0; k < 8; ++k) {
        int row = sj + k;  // j-row 0..31
        unsigned swz2 =
            (unsigned)(((row & 7) << 4) ^ (((row >> 3) & 3) << 5));
        *(u16*)(T2 + row * 128 + ((unsigned)(lc * 2) ^ swz2)) = pv[k];
      }
    }
    if (c < 7) {
#pragma unroll
      for (int u = 0; u < 4; ++u)
        pf2[u] = *(const uint4*)(h2base +
                                 (size_t)((c + 1) * 64 + u * 16) * 512);
    }
#pragma unroll
    for (int kk = 0; kk < 2; ++kk) {
      int kb = c * 128 + kk * 64 + g * 16;  // byte in W row (l*2)
      bf16x8 a = *(const bf16x8*)(W_lds + n * 1024 + (kb ^ asw));
      int lb2 = kk * 64 + g * 16;  // byte in T2 row (local l*2)
      {
        int j = 0 * 16 + n;
        unsigned swz2 = (unsigned)(((j & 7) << 4) ^ (((j >> 3) & 3) << 5));
        bf16x8 bb = *(const bf16x8*)(T2 + j * 128 + ((unsigned)lb2 ^ swz2));
        ac20 = __builtin_amdgcn_mfma_f32_16x16x32_bf16(a, bb, ac20, 0, 0, 0);
      }
      {
        int j = 1 * 16 + n;
        unsigned swz2 = (unsigned)(((j & 7) << 4) ^ (((j >> 3) & 3) << 5));
        bf16x8 bb = *(const bf16x8*)(T2 + j * 128 + ((unsigned)lb2 ^ swz2));
        ac21 = __builtin_amdgcn_mfma_f32_16x16x32_bf16(a, bb, ac21, 0, 0, 0);
      }
    }
  }
  // epilogue: C[r=g*4+i][j = jw0 + nt*16 + n]
#pragma unroll
  for (int i = 0; i < 4; ++i) {
    G[((size_t)b * Rn + r0 + g * 4 + i) * 512 + jw0 + n] = ac20[i];
    G[((size_t)b * Rn + r0 + g * 4 + i) * 512 + jw0 + 16 + n] = ac21[i];
  }
}

// ---------------------------------------------------------------------------
// K3: out[b,(m,h),s] = dot(v[m, h*64+s, :], G[b, r, :]) + vb[m, h*64+s]
// grid 1024; all 4 v-rows loaded upfront per wave (one HBM latency).
// ---------------------------------------------------------------------------
__global__ __launch_bounds__(256) void out_kernel(
    const float* __restrict__ v, const float* __restrict__ vb,
    const float* __restrict__ G, float* __restrict__ out) {
  int bid = blockIdx.x;
  int sc = bid & 3, hh = (bid >> 2) & 7, m = bid >> 5;
  int r = m * Hn + hh;
  __shared__ float Gs[Bn][EMBn];
  int tid = threadIdx.x;
#pragma unroll
  for (int i = 0; i < 2; ++i) {
    int idx4 = tid + i * 256;
    int bb = idx4 >> 7, e4 = (idx4 & 127) << 2;
    *(float4*)&Gs[bb][e4] =
        *(const float4*)&G[((size_t)bb * Rn + r) * EMBn + e4];
  }
  __syncthreads();
  int wid = tid >> 6, lane = tid & 63;
  const float* vbase =
      v + ((size_t)m * EMBn + hh * HSn + sc * 16 + wid * 4) * EMBn + lane * 8;
  float4 va[8];
#pragma unroll
  for (int i = 0; i < 4; ++i) {
    va[2 * i] = *(const float4*)(vbase + (size_t)i * EMBn);
    va[2 * i + 1] = *(const float4*)(vbase + (size_t)i * EMBn + 4);
  }
#pragma unroll
  for (int i = 0; i < 4; ++i) {
    int rr = sc * 16 + wid * 4 + i;
    float acc[Bn];
#pragma unroll
    for (int bb = 0; bb < Bn; ++bb) {
      const float* gp = &Gs[bb][lane * 8];
      float4 g0 = *(const float4*)gp;
      float4 g1 = *(const float4*)(gp + 4);
      acc[bb] = va[2 * i].x * g0.x + va[2 * i].y * g0.y +
                va[2 * i].z * g0.z + va[2 * i].w * g0.w +
                va[2 * i + 1].x * g1.x + va[2 * i + 1].y * g1.y +
                va[2 * i + 1].z * g1.z + va[2 * i + 1].w * g1.w;
    }
#pragma unroll
    for (int off = 1; off < 64; off <<= 1) {
#pragma unroll
      for (int bb = 0; bb < Bn; ++bb) acc[bb] += __shfl_xor(acc[bb], off, 64);
    }
    if (lane == 0) {
      float vbv = vb[(size_t)m * EMBn + hh * HSn + rr];
#pragma unroll
      for (int bb = 0; bb < Bn; ++bb) {
        out[(((size_t)bb * Hn + hh) * Mn + m) * HSn + rr] = acc[bb] + vbv;
      }
    }
  }
}

extern "C" void kernel_launch(void* const* d_in, const int* in_sizes, int n_in,
                              void* d_out, int out_size, void* d_ws,
                              size_t ws_size, hipStream_t stream) {
  const float* x = (const float*)d_in[0];
  const float* cells = (const float*)d_in[1];
  const float* q_w = (const float*)d_in[2];
  const float* q_b = (const float*)d_in[3];
  const float* v = (const float*)d_in[4];
  const float* vbp = (const float*)d_in[5];
  const float* ln_g = (const float*)d_in[6];
  const float* ln_b = (const float*)d_in[7];
  float* out = (float*)d_out;

  u16* hb = (u16*)d_ws;                          // B*L*EMB bf16 = 2 MB
  u16* Pb = hb + (size_t)Bn * Ln * EMBn;         // 256 KB
  float* pb = (float*)(Pb + (size_t)Rn * EMBn);  // 1 KB
  float* G = pb + Rn;                            // B*R*EMB f32 = 2 MB

  ln_pproj_kernel<<<768, 256, 0, stream>>>(x, ln_g, ln_b, cells, q_w, q_b, hb,
                                           Pb, pb);
  fused_kernel<<<128, 512, 0, stream>>>(hb, Pb, pb, G);
  out_kernel<<<1024, 256, 0, stream>>>(v, vbp, G, out);
}

// Round 9
// 37.608 us; speedup vs baseline: 7.5666x; 1.0513x over previous
//
#include <hip/hip_runtime.h>

typedef unsigned short u16;
typedef float f32x4 __attribute__((ext_vector_type(4)));
typedef short bf16x8 __attribute__((ext_vector_type(8)));

constexpr int Bn = 4, Ln = 512, Mn = 32, EMBn = 512, Hn = 8, HSn = 64;
constexpr int Rn = Mn * Hn; // 256

__device__ __forceinline__ float wave_sum(float v) {
#pragma unroll
  for (int off = 1; off < 64; off <<= 1) v += __shfl_xor(v, off, 64);
  return v;
}
__device__ __forceinline__ u16 f2bf(float f) {
  unsigned u = __float_as_uint(f);
  unsigned r = (u + 0x7FFFu + ((u >> 16) & 1u)) >> 16;
  return (u16)r;
}
__device__ __forceinline__ unsigned pack2(float a, float b) {
  return (unsigned)f2bf(a) | ((unsigned)f2bf(b) << 16);
}

// ---------------------------------------------------------------------------
// K1: blocks [0,512): LayerNorm -> h_bf16. blocks [512,768): P = cells*q_w.
// (proven since R1)
// ---------------------------------------------------------------------------
__global__ __launch_bounds__(256) void ln_pproj_kernel(
    const float* __restrict__ x, const float* __restrict__ gam,
    const float* __restrict__ bet, const float* __restrict__ cells,
    const float* __restrict__ q_w, const float* __restrict__ q_b,
    u16* __restrict__ hb, u16* __restrict__ Pb, float* __restrict__ pb) {
  int bid = blockIdx.x, tid = threadIdx.x;
  __shared__ float cs[HSn];
  if (bid < 512) {
    int row = bid * 4 + (tid >> 6), lane = tid & 63;
    const float* xr = x + (size_t)row * EMBn + lane * 8;
    float4 a0 = *(const float4*)xr;
    float4 a1 = *(const float4*)(xr + 4);
    float s = a0.x + a0.y + a0.z + a0.w + a1.x + a1.y + a1.z + a1.w;
    float ss = a0.x * a0.x + a0.y * a0.y + a0.z * a0.z + a0.w * a0.w +
               a1.x * a1.x + a1.y * a1.y + a1.z * a1.z + a1.w * a1.w;
    s = wave_sum(s);
    ss = wave_sum(ss);
    float mu = s * (1.0f / EMBn);
    float var = ss * (1.0f / EMBn) - mu * mu;
    float rstd = rsqrtf(var + 1e-5f);
    const float* gp = gam + lane * 8;
    const float* bp = bet + lane * 8;
    float4 g0 = *(const float4*)gp, g1 = *(const float4*)(gp + 4);
    float4 b0 = *(const float4*)bp, b1 = *(const float4*)(bp + 4);
    float4 o0, o1;
    o0.x = (a0.x - mu) * rstd * g0.x + b0.x;
    o0.y = (a0.y - mu) * rstd * g0.y + b0.y;
    o0.z = (a0.z - mu) * rstd * g0.z + b0.z;
    o0.w = (a0.w - mu) * rstd * g0.w + b0.w;
    o1.x = (a1.x - mu) * rstd * g1.x + b1.x;
    o1.y = (a1.y - mu) * rstd * g1.y + b1.y;
    o1.z = (a1.z - mu) * rstd * g1.z + b1.z;
    o1.w = (a1.w - mu) * rstd * g1.w + b1.w;
    uint4 st;
    st.x = pack2(o0.x, o0.y);
    st.y = pack2(o0.z, o0.w);
    st.z = pack2(o1.x, o1.y);
    st.w = pack2(o1.z, o1.w);
    *(uint4*)&hb[(size_t)row * EMBn + lane * 8] = st;
  } else {
    int r = bid - 512;
    int hh = r & 7;
    if (tid < HSn) cs[tid] = cells[(size_t)r * HSn + tid];
    __syncthreads();
    for (int e = tid; e < EMBn; e += 256) {
      float acc = 0.f;
#pragma unroll 8
      for (int s2 = 0; s2 < HSn; ++s2)
        acc += cs[s2] * q_w[(size_t)(hh * HSn + s2) * EMBn + e];
      Pb[(size_t)r * EMBn + e] = f2bf(acc);
    }
    if (tid == 0) {
      float a = 0.f;
      for (int s2 = 0; s2 < HSn; ++s2) a += cs[s2] * q_b[hh * HSn + s2];
      pb[r] = a;
    }
  }
}

// ---------------------------------------------------------------------------
// MFMA GEMM core: C tile 32x64 = A[32xK] * B^T[64xK], K=512, strides 512.
// LDS-staged, double-buffered, XOR-swizzled, 256 threads. (proven R2/R3)
// MODE 0: C f32 (gmat).  MODE 1: C = bf16 exp((x+pb)*0.125) (unnormalized
// softmax numerator) + deterministic per-(row, 32-col slot) partial sums
// into spart[r*16 + slot].
// ---------------------------------------------------------------------------
template <int MODE>
__device__ __forceinline__ void gemm_core(const u16* __restrict__ Ag,
                                          const u16* __restrict__ Bg,
                                          void* __restrict__ Cgv,
                                          const float* __restrict__ pbv,
                                          float* __restrict__ spart,
                                          int r0, int n0, int tid,
                                          u16* smem) {
  const int wave = tid >> 6, lane = tid & 63;
  const int srow = lane >> 3, sblk = lane & 7;
  const u16* gsrc0;
  const u16* gsrc1;
  const u16* gsrc2;
  unsigned lofs0, lofs1, lofs2, lstep0, lstep1, lstep2;
  {
    int id0 = wave * 3;
#pragma unroll
    for (int q = 0; q < 3; ++q) {
      int id = id0 + q;
      const u16* g;
      unsigned lo, ls;
      if (id < 4) {
        int row = id * 8 + srow;
        g = Ag + (size_t)(r0 + row) * 512 + sblk * 8;
        lo = row * 64 + (((sblk * 16) ^ ((row & 7) << 4)) >> 1);
        ls = 2048;
      } else {
        int row = (id - 4) * 8 + srow;
        g = Bg + (size_t)(n0 + row) * 512 + sblk * 8;
        lo = 4096 + row * 64 + (((sblk * 16) ^ ((row & 7) << 4)) >> 1);
        ls = 4096;
      }
      if (q == 0) { gsrc0 = g; lofs0 = lo; lstep0 = ls; }
      else if (q == 1) { gsrc1 = g; lofs1 = lo; lstep1 = ls; }
      else { gsrc2 = g; lofs2 = lo; lstep2 = ls; }
    }
  }
  uint4 rv0 = *(const uint4*)gsrc0;
  uint4 rv1 = *(const uint4*)gsrc1;
  uint4 rv2 = *(const uint4*)gsrc2;
  *(uint4*)&smem[lofs0] = rv0;
  *(uint4*)&smem[lofs1] = rv1;
  *(uint4*)&smem[lofs2] = rv2;
  __syncthreads();

  f32x4 acc0 = {0.f, 0.f, 0.f, 0.f};
  f32x4 acc1 = {0.f, 0.f, 0.f, 0.f};
  const int ra = (wave >> 1) * 16 + (lane & 15);
  const int nb = (wave & 1) * 32 + (lane & 15);
  const unsigned asw = (unsigned)((ra & 7) << 4);
  const unsigned bsw = (unsigned)((nb & 7) << 4);
  const unsigned kg = (unsigned)((lane >> 4) * 16);

#pragma unroll
  for (int c = 0; c < 8; ++c) {
    const int cur = c & 1;
    if (c < 7) {
      rv0 = *(const uint4*)(gsrc0 + (c + 1) * 64);
      rv1 = *(const uint4*)(gsrc1 + (c + 1) * 64);
      rv2 = *(const uint4*)(gsrc2 + (c + 1) * 64);
    }
    const char* Ab = (const char*)(smem + cur * 2048);
    const char* Bb = (const char*)(smem + 4096 + cur * 4096);
#pragma unroll
    for (int ks = 0; ks < 2; ++ks) {
      unsigned kb = ks * 64 + kg;
      bf16x8 a = *(const bf16x8*)(Ab + ra * 128 + (kb ^ asw));
      bf16x8 b0 = *(const bf16x8*)(Bb + nb * 128 + (kb ^ bsw));
      bf16x8 b1 = *(const bf16x8*)(Bb + (nb + 16) * 128 + (kb ^ bsw));
      acc0 = __builtin_amdgcn_mfma_f32_16x16x32_bf16(a, b0, acc0, 0, 0, 0);
      acc1 = __builtin_amdgcn_mfma_f32_16x16x32_bf16(a, b1, acc1, 0, 0, 0);
    }
    if (c < 7) {
      unsigned bo = (unsigned)(cur ^ 1);
      *(uint4*)&smem[lofs0 + bo * lstep0] = rv0;
      *(uint4*)&smem[lofs1 + bo * lstep1] = rv1;
      *(uint4*)&smem[lofs2 + bo * lstep2] = rv2;
    }
    __syncthreads();
  }

  const int rg = r0 + (wave >> 1) * 16 + ((lane >> 4) << 2);
  const int cg = n0 + (wave & 1) * 32 + (lane & 15);
  if (MODE == 0) {
    float* Cg = (float*)Cgv;
#pragma unroll
    for (int j = 0; j < 4; ++j) {
      Cg[(size_t)(rg + j) * 512 + cg] = acc0[j];
      Cg[(size_t)(rg + j) * 512 + cg + 16] = acc1[j];
    }
  } else {
    u16* Cg = (u16*)Cgv;
    float rs[4];
#pragma unroll
    for (int j = 0; j < 4; ++j) {
      float pv = pbv[rg + j];
      float e0 = __expf((acc0[j] + pv) * 0.125f);
      float e1 = __expf((acc1[j] + pv) * 0.125f);
      Cg[(size_t)(rg + j) * 512 + cg] = f2bf(e0);
      Cg[(size_t)(rg + j) * 512 + cg + 16] = f2bf(e1);
      rs[j] = e0 + e1;
    }
#pragma unroll
    for (int off = 1; off < 16; off <<= 1) {
#pragma unroll
      for (int j = 0; j < 4; ++j) rs[j] += __shfl_xor(rs[j], off, 64);
    }
    if ((lane & 15) == 0) {
      int slot = (n0 >> 6) * 2 + (wave & 1);
#pragma unroll
      for (int j = 0; j < 4; ++j) spart[(unsigned)(rg + j) * 16 + slot] = rs[j];
    }
  }
}

// ---------------------------------------------------------------------------
// K2: blocks [0,256): E = exp((P.h^T + pb)/8) bf16 + row partial sums.
//     blocks [256,512): transpose h -> htb[b][j][l] (bf16).
// ---------------------------------------------------------------------------
__global__ __launch_bounds__(256) void escore_trans_kernel(
    const u16* __restrict__ hb, const u16* __restrict__ Pb,
    const float* __restrict__ pb, u16* __restrict__ Eb,
    float* __restrict__ spart, u16* __restrict__ htb) {
  __shared__ u16 smem[12288];
  int bid = blockIdx.x, tid = threadIdx.x;
  if (bid < 256) {
    int b = bid >> 6, rem = bid & 63;
    int r0 = (rem >> 3) * 32, l0 = (rem & 7) * 64;
    gemm_core<1>(Pb, hb + (size_t)b * Ln * EMBn, Eb + (size_t)b * Rn * Ln, pb,
                 spart + (size_t)b * Rn * 16, r0, l0, tid, smem);
  } else {
    int t = bid - 256;
    int b = t >> 6, rem = t & 63;
    int l0 = (rem >> 3) * 64, j0 = (rem & 7) * 64;
    u16(*ts)[65] = (u16(*)[65])smem;
#pragma unroll
    for (int i = 0; i < 4; ++i) {
      int idx = tid + i * 256;
      int row = idx >> 4, c4 = (idx & 15) * 4;
      uint2 u = *(const uint2*)&hb[(size_t)(b * Ln + l0 + row) * EMBn + j0 + c4];
      ts[row][c4] = (u16)(u.x & 0xffffu);
      ts[row][c4 + 1] = (u16)(u.x >> 16);
      ts[row][c4 + 2] = (u16)(u.y & 0xffffu);
      ts[row][c4 + 3] = (u16)(u.y >> 16);
    }
    __syncthreads();
#pragma unroll
    for (int i = 0; i < 4; ++i) {
      int idx = tid + i * 256;
      int jr = idx >> 4, lc4 = (idx & 15) * 4;
      unsigned lo = (unsigned)ts[lc4][jr] | ((unsigned)ts[lc4 + 1][jr] << 16);
      unsigned hi = (unsigned)ts[lc4 + 2][jr] | ((unsigned)ts[lc4 + 3][jr] << 16);
      uint2 u;
      u.x = lo;
      u.y = hi;
      *(uint2*)&htb[(size_t)(b * EMBn + j0 + jr) * Ln + l0 + lc4] = u;
    }
  }
}

// ---------------------------------------------------------------------------
// K3: G'[b][r][j] = sum_l E[b][r][l] * ht[b][j][l]  (unnormalized)
// ---------------------------------------------------------------------------
__global__ __launch_bounds__(256) void gmat_kernel(const u16* __restrict__ Eb,
                                                   const u16* __restrict__ htb,
                                                   float* __restrict__ G) {
  __shared__ u16 smem[12288];
  int bid = blockIdx.x, tid = threadIdx.x;
  int b = bid >> 6, rem = bid & 63;
  int r0 = (rem >> 3) * 32, j0 = (rem & 7) * 64;
  gemm_core<0>(Eb + (size_t)b * Rn * Ln, htb + (size_t)b * EMBn * Ln,
               G + (size_t)b * Rn * EMBn, nullptr, nullptr, r0, j0, tid, smem);
}

// ---------------------------------------------------------------------------
// K4: out[b,(m,h),s] = dot(v[m,h*64+s,:], G'[b,r,:]) / s_r + vb[m,h*64+s]
// ---------------------------------------------------------------------------
__global__ __launch_bounds__(256) void out_kernel(
    const float* __restrict__ v, const float* __restrict__ vb,
    const float* __restrict__ G, const float* __restrict__ spart,
    float* __restrict__ out) {
  int bid = blockIdx.x;
  int sc = bid & 3, hh = (bid >> 2) & 7, m = bid >> 5;
  int r = m * Hn + hh;
  __shared__ float Gs[Bn][EMBn];
  __shared__ float sInv[Bn];
  int tid = threadIdx.x;
#pragma unroll
  for (int i = 0; i < 2; ++i) {
    int idx4 = tid + i * 256;
    int bb = idx4 >> 7, e4 = (idx4 & 127) << 2;
    *(float4*)&Gs[bb][e4] =
        *(const float4*)&G[((size_t)bb * Rn + r) * EMBn + e4];
  }
  if (tid < 64) {
    int bb = tid >> 4, k = tid & 15;
    float p = spart[((size_t)bb * Rn + r) * 16 + k];
#pragma unroll
    for (int off = 1; off < 16; off <<= 1) p += __shfl_xor(p, off, 64);
    if (k == 0) sInv[bb] = 1.0f / p;
  }
  __syncthreads();
  int wid = tid >> 6, lane = tid & 63;
  const float* vbase =
      v + ((size_t)m * EMBn + hh * HSn + sc * 16 + wid * 4) * EMBn + lane * 8;
  float4 va[8];
#pragma unroll
  for (int i = 0; i < 4; ++i) {
    va[2 * i] = *(const float4*)(vbase + (size_t)i * EMBn);
    va[2 * i + 1] = *(const float4*)(vbase + (size_t)i * EMBn + 4);
  }
#pragma unroll
  for (int i = 0; i < 4; ++i) {
    int rr = sc * 16 + wid * 4 + i;
    float acc[Bn];
#pragma unroll
    for (int bb = 0; bb < Bn; ++bb) {
      const float* gp = &Gs[bb][lane * 8];
      float4 g0 = *(const float4*)gp;
      float4 g1 = *(const float4*)(gp + 4);
      acc[bb] = va[2 * i].x * g0.x + va[2 * i].y * g0.y +
                va[2 * i].z * g0.z + va[2 * i].w * g0.w +
                va[2 * i + 1].x * g1.x + va[2 * i + 1].y * g1.y +
                va[2 * i + 1].z * g1.z + va[2 * i + 1].w * g1.w;
    }
#pragma unroll
    for (int off = 1; off < 64; off <<= 1) {
#pragma unroll
      for (int bb = 0; bb < Bn; ++bb) acc[bb] += __shfl_xor(acc[bb], off, 64);
    }
    if (lane == 0) {
      float vbv = vb[(size_t)m * EMBn + hh * HSn + rr];
#pragma unroll
      for (int bb = 0; bb < Bn; ++bb) {
        out[(((size_t)bb * Hn + hh) * Mn + m) * HSn + rr] =
            acc[bb] * sInv[bb] + vbv;
      }
    }
  }
}

extern "C" void kernel_launch(void* const* d_in, const int* in_sizes, int n_in,
                              void* d_out, int out_size, void* d_ws,
                              size_t ws_size, hipStream_t stream) {
  const float* x = (const float*)d_in[0];
  const float* cells = (const float*)d_in[1];
  const float* q_w = (const float*)d_in[2];
  const float* q_b = (const float*)d_in[3];
  const float* v = (const float*)d_in[4];
  const float* vbp = (const float*)d_in[5];
  const float* ln_g = (const float*)d_in[6];
  const float* ln_b = (const float*)d_in[7];
  float* out = (float*)d_out;

  u16* hb = (u16*)d_ws;                            // 2 MB
  u16* htb = hb + (size_t)Bn * Ln * EMBn;          // 2 MB
  u16* Pb = htb + (size_t)Bn * Ln * EMBn;          // 256 KB
  u16* Eb = Pb + (size_t)Rn * EMBn;                // 1 MB (bf16 E)
  float* pb = (float*)(Eb + (size_t)Bn * Rn * Ln); // 1 KB
  float* spart = pb + Rn;                          // 4*256*16 f32 = 64 KB
  float* G = spart + (size_t)Bn * Rn * 16;         // 2 MB

  ln_pproj_kernel<<<768, 256, 0, stream>>>(x, ln_g, ln_b, cells, q_w, q_b, hb,
                                           Pb, pb);
  escore_trans_kernel<<<512, 256, 0, stream>>>(hb, Pb, pb, Eb, spart, htb);
  gmat_kernel<<<256, 256, 0, stream>>>(Eb, htb, G);
  out_kernel<<<1024, 256, 0, stream>>>(v, vbp, G, spart, out);
}

// Round 10
// 36.988 us; speedup vs baseline: 7.6934x; 1.0168x over previous
//
#include <hip/hip_runtime.h>

typedef unsigned short u16;
typedef float f32x4 __attribute__((ext_vector_type(4)));
typedef short bf16x8 __attribute__((ext_vector_type(8)));

constexpr int Bn = 4, Ln = 512, Mn = 32, EMBn = 512, Hn = 8, HSn = 64;
constexpr int Rn = Mn * Hn; // 256

__device__ __forceinline__ float wave_sum(float v) {
#pragma unroll
  for (int off = 1; off < 64; off <<= 1) v += __shfl_xor(v, off, 64);
  return v;
}
__device__ __forceinline__ u16 f2bf(float f) {
  unsigned u = __float_as_uint(f);
  unsigned r = (u + 0x7FFFu + ((u >> 16) & 1u)) >> 16;
  return (u16)r;
}
__device__ __forceinline__ unsigned pack2(float a, float b) {
  return (unsigned)f2bf(a) | ((unsigned)f2bf(b) << 16);
}

// ---------------------------------------------------------------------------
// K1: blocks [0,512): LayerNorm -> h_bf16. blocks [512,768): P = cells*q_w.
// (proven since R1)
// ---------------------------------------------------------------------------
__global__ __launch_bounds__(256) void ln_pproj_kernel(
    const float* __restrict__ x, const float* __restrict__ gam,
    const float* __restrict__ bet, const float* __restrict__ cells,
    const float* __restrict__ q_w, const float* __restrict__ q_b,
    u16* __restrict__ hb, u16* __restrict__ Pb, float* __restrict__ pb) {
  int bid = blockIdx.x, tid = threadIdx.x;
  __shared__ float cs[HSn];
  if (bid < 512) {
    int row = bid * 4 + (tid >> 6), lane = tid & 63;
    const float* xr = x + (size_t)row * EMBn + lane * 8;
    float4 a0 = *(const float4*)xr;
    float4 a1 = *(const float4*)(xr + 4);
    float s = a0.x + a0.y + a0.z + a0.w + a1.x + a1.y + a1.z + a1.w;
    float ss = a0.x * a0.x + a0.y * a0.y + a0.z * a0.z + a0.w * a0.w +
               a1.x * a1.x + a1.y * a1.y + a1.z * a1.z + a1.w * a1.w;
    s = wave_sum(s);
    ss = wave_sum(ss);
    float mu = s * (1.0f / EMBn);
    float var = ss * (1.0f / EMBn) - mu * mu;
    float rstd = rsqrtf(var + 1e-5f);
    const float* gp = gam + lane * 8;
    const float* bp = bet + lane * 8;
    float4 g0 = *(const float4*)gp, g1 = *(const float4*)(gp + 4);
    float4 b0 = *(const float4*)bp, b1 = *(const float4*)(bp + 4);
    float4 o0, o1;
    o0.x = (a0.x - mu) * rstd * g0.x + b0.x;
    o0.y = (a0.y - mu) * rstd * g0.y + b0.y;
    o0.z = (a0.z - mu) * rstd * g0.z + b0.z;
    o0.w = (a0.w - mu) * rstd * g0.w + b0.w;
    o1.x = (a1.x - mu) * rstd * g1.x + b1.x;
    o1.y = (a1.y - mu) * rstd * g1.y + b1.y;
    o1.z = (a1.z - mu) * rstd * g1.z + b1.z;
    o1.w = (a1.w - mu) * rstd * g1.w + b1.w;
    uint4 st;
    st.x = pack2(o0.x, o0.y);
    st.y = pack2(o0.z, o0.w);
    st.z = pack2(o1.x, o1.y);
    st.w = pack2(o1.z, o1.w);
    *(uint4*)&hb[(size_t)row * EMBn + lane * 8] = st;
  } else {
    int r = bid - 512;
    int hh = r & 7;
    if (tid < HSn) cs[tid] = cells[(size_t)r * HSn + tid];
    __syncthreads();
    for (int e = tid; e < EMBn; e += 256) {
      float acc = 0.f;
#pragma unroll 8
      for (int s2 = 0; s2 < HSn; ++s2)
        acc += cs[s2] * q_w[(size_t)(hh * HSn + s2) * EMBn + e];
      Pb[(size_t)r * EMBn + e] = f2bf(acc);
    }
    if (tid == 0) {
      float a = 0.f;
      for (int s2 = 0; s2 < HSn; ++s2) a += cs[s2] * q_b[hh * HSn + s2];
      pb[r] = a;
    }
  }
}

// ---------------------------------------------------------------------------
// 32x32 MFMA GEMM core: C[r0..+32][n0..+32] = A[32xK]*B^T[32xK], K=512.
// 256 thr, 4 waves (2x2 quadrants of 16x16). LDS 16 KB (A,B dbuf, swizzled).
// MODE 0: C f32.  MODE 1: C = bf16 exp((x+pb)*0.125) + partial row sums into
// spart[r*32 + slot], slot = (n0>>4)+wc (32 slots of 16 cols).
// ---------------------------------------------------------------------------
template <int MODE>
__device__ __forceinline__ void gemm_core32(const u16* __restrict__ Ag,
                                            const u16* __restrict__ Bg,
                                            void* __restrict__ Cgv,
                                            const float* __restrict__ pbv,
                                            float* __restrict__ spart,
                                            int r0, int n0, int tid,
                                            u16* smem) {
  const int wave = tid >> 6, lane = tid & 63;
  const int srow = tid >> 3, sblk = tid & 7;  // 32 rows x 8 k-blocks
  const u16* gsrcA = Ag + (size_t)(r0 + srow) * 512 + sblk * 8;
  const u16* gsrcB = Bg + (size_t)(n0 + srow) * 512 + sblk * 8;
  const unsigned lswz = (unsigned)(((sblk * 16) ^ ((srow & 7) << 4)) >> 1);
  const unsigned lofsA = (unsigned)(srow * 64) + lswz;
  const unsigned lofsB = 4096u + (unsigned)(srow * 64) + lswz;

  uint4 rvA = *(const uint4*)gsrcA;
  uint4 rvB = *(const uint4*)gsrcB;
  *(uint4*)&smem[lofsA] = rvA;
  *(uint4*)&smem[lofsB] = rvB;
  __syncthreads();

  f32x4 acc = {0.f, 0.f, 0.f, 0.f};
  const int wr = wave >> 1, wc = wave & 1;
  const int ra = wr * 16 + (lane & 15);
  const int nb = wc * 16 + (lane & 15);
  const unsigned asw = (unsigned)((ra & 7) << 4);
  const unsigned bsw = (unsigned)((nb & 7) << 4);
  const unsigned kg = (unsigned)((lane >> 4) * 16);

#pragma unroll
  for (int c = 0; c < 8; ++c) {
    const int cur = c & 1;
    if (c < 7) {
      rvA = *(const uint4*)(gsrcA + (c + 1) * 64);
      rvB = *(const uint4*)(gsrcB + (c + 1) * 64);
    }
    const char* Ab = (const char*)(smem + cur * 2048);
    const char* Bb = (const char*)(smem + 4096 + cur * 2048);
#pragma unroll
    for (int ks = 0; ks < 2; ++ks) {
      unsigned kb = ks * 64 + kg;
      bf16x8 a = *(const bf16x8*)(Ab + ra * 128 + (kb ^ asw));
      bf16x8 b0 = *(const bf16x8*)(Bb + nb * 128 + (kb ^ bsw));
      acc = __builtin_amdgcn_mfma_f32_16x16x32_bf16(a, b0, acc, 0, 0, 0);
    }
    if (c < 7) {
      unsigned bo = (unsigned)((cur ^ 1) * 2048);
      *(uint4*)&smem[lofsA + bo] = rvA;
      *(uint4*)&smem[lofsB + bo] = rvB;
    }
    __syncthreads();
  }

  const int rg = r0 + wr * 16 + ((lane >> 4) << 2);
  const int cg = n0 + wc * 16 + (lane & 15);
  if (MODE == 0) {
    float* Cg = (float*)Cgv;
#pragma unroll
    for (int j = 0; j < 4; ++j) Cg[(size_t)(rg + j) * 512 + cg] = acc[j];
  } else {
    u16* Cg = (u16*)Cgv;
    float rs[4];
#pragma unroll
    for (int j = 0; j < 4; ++j) {
      float pv = pbv[rg + j];
      float e0 = __expf((acc[j] + pv) * 0.125f);
      Cg[(size_t)(rg + j) * 512 + cg] = f2bf(e0);
      rs[j] = e0;
    }
#pragma unroll
    for (int off = 1; off < 16; off <<= 1) {
#pragma unroll
      for (int j = 0; j < 4; ++j) rs[j] += __shfl_xor(rs[j], off, 64);
    }
    if ((lane & 15) == 0) {
      int slot = (n0 >> 4) + wc;
#pragma unroll
      for (int j = 0; j < 4; ++j) spart[(unsigned)(rg + j) * 32 + slot] = rs[j];
    }
  }
}

// ---------------------------------------------------------------------------
// K2: blocks [0,512): E = exp((P.h^T+pb)/8) bf16 + partial sums (32x32 tiles)
//     blocks [512,768): transpose h -> htb[b][j][l].
// ---------------------------------------------------------------------------
__global__ __launch_bounds__(256) void escore_trans_kernel(
    const u16* __restrict__ hb, const u16* __restrict__ Pb,
    const float* __restrict__ pb, u16* __restrict__ Eb,
    float* __restrict__ spart, u16* __restrict__ htb) {
  __shared__ u16 smem[8192];
  int bid = blockIdx.x, tid = threadIdx.x;
  if (bid < 512) {
    int b = bid >> 7, rem = bid & 127;
    int r0 = (rem >> 4) * 32, l0 = (rem & 15) * 32;
    gemm_core32<1>(Pb, hb + (size_t)b * Ln * EMBn, Eb + (size_t)b * Rn * Ln,
                   pb, spart + (size_t)b * Rn * 32, r0, l0, tid, smem);
  } else {
    int t = bid - 512;
    int b = t >> 6, rem = t & 63;
    int l0 = (rem >> 3) * 64, j0 = (rem & 7) * 64;
    u16(*ts)[65] = (u16(*)[65])smem;
#pragma unroll
    for (int i = 0; i < 4; ++i) {
      int idx = tid + i * 256;
      int row = idx >> 4, c4 = (idx & 15) * 4;
      uint2 u = *(const uint2*)&hb[(size_t)(b * Ln + l0 + row) * EMBn + j0 + c4];
      ts[row][c4] = (u16)(u.x & 0xffffu);
      ts[row][c4 + 1] = (u16)(u.x >> 16);
      ts[row][c4 + 2] = (u16)(u.y & 0xffffu);
      ts[row][c4 + 3] = (u16)(u.y >> 16);
    }
    __syncthreads();
#pragma unroll
    for (int i = 0; i < 4; ++i) {
      int idx = tid + i * 256;
      int jr = idx >> 4, lc4 = (idx & 15) * 4;
      unsigned lo = (unsigned)ts[lc4][jr] | ((unsigned)ts[lc4 + 1][jr] << 16);
      unsigned hi = (unsigned)ts[lc4 + 2][jr] | ((unsigned)ts[lc4 + 3][jr] << 16);
      uint2 u;
      u.x = lo;
      u.y = hi;
      *(uint2*)&htb[(size_t)(b * EMBn + j0 + jr) * Ln + l0 + lc4] = u;
    }
  }
}

// ---------------------------------------------------------------------------
// K3: G'[b][r][j] = sum_l E[b][r][l] * ht[b][j][l]  (32x32 tiles, 512 blocks)
// ---------------------------------------------------------------------------
__global__ __launch_bounds__(256) void gmat_kernel(const u16* __restrict__ Eb,
                                                   const u16* __restrict__ htb,
                                                   float* __restrict__ G) {
  __shared__ u16 smem[8192];
  int bid = blockIdx.x, tid = threadIdx.x;
  int b = bid >> 7, rem = bid & 127;
  int r0 = (rem >> 4) * 32, j0 = (rem & 15) * 32;
  gemm_core32<0>(Eb + (size_t)b * Rn * Ln, htb + (size_t)b * EMBn * Ln,
                 G + (size_t)b * Rn * EMBn, nullptr, nullptr, r0, j0, tid,
                 smem);
}

// ---------------------------------------------------------------------------
// K4: out[b,(m,h),s] = dot(v[m,h*64+s,:], G'[b,r,:]) / s_r + vb[m,h*64+s]
// grid 2048 (m x hh x 8 s-chunks of 8 rows); 8 blocks/CU for HBM v stream.
// ---------------------------------------------------------------------------
__global__ __launch_bounds__(256) void out_kernel(
    const float* __restrict__ v, const float* __restrict__ vb,
    const float* __restrict__ G, const float* __restrict__ spart,
    float* __restrict__ out) {
  int bid = blockIdx.x;
  int sc = bid & 7, hh = (bid >> 3) & 7, m = bid >> 6;
  int r = m * Hn + hh;
  __shared__ float Gs[Bn][EMBn];
  __shared__ float sInv[Bn];
  int tid = threadIdx.x;
#pragma unroll
  for (int i = 0; i < 2; ++i) {
    int idx4 = tid + i * 256;
    int bb = idx4 >> 7, e4 = (idx4 & 127) << 2;
    *(float4*)&Gs[bb][e4] =
        *(const float4*)&G[((size_t)bb * Rn + r) * EMBn + e4];
  }
  if (tid < 128) {
    int bb = tid >> 5, k = tid & 31;
    float p = spart[((size_t)bb * Rn + r) * 32 + k];
#pragma unroll
    for (int off = 1; off < 32; off <<= 1) p += __shfl_xor(p, off, 64);
    if (k == 0) sInv[bb] = 1.0f / p;
  }
  __syncthreads();
  int wid = tid >> 6, lane = tid & 63;
  const float* vbase =
      v + ((size_t)m * EMBn + hh * HSn + sc * 8 + wid * 2) * EMBn + lane * 8;
  float4 va[4];
#pragma unroll
  for (int i = 0; i < 2; ++i) {
    va[2 * i] = *(const float4*)(vbase + (size_t)i * EMBn);
    va[2 * i + 1] = *(const float4*)(vbase + (size_t)i * EMBn + 4);
  }
#pragma unroll
  for (int i = 0; i < 2; ++i) {
    int rr = sc * 8 + wid * 2 + i;
    float acc[Bn];
#pragma unroll
    for (int bb = 0; bb < Bn; ++bb) {
      const float* gp = &Gs[bb][lane * 8];
      float4 g0 = *(const float4*)gp;
      float4 g1 = *(const float4*)(gp + 4);
      acc[bb] = va[2 * i].x * g0.x + va[2 * i].y * g0.y +
                va[2 * i].z * g0.z + va[2 * i].w * g0.w +
                va[2 * i + 1].x * g1.x + va[2 * i + 1].y * g1.y +
                va[2 * i + 1].z * g1.z + va[2 * i + 1].w * g1.w;
    }
#pragma unroll
    for (int off = 1; off < 64; off <<= 1) {
#pragma unroll
      for (int bb = 0; bb < Bn; ++bb) acc[bb] += __shfl_xor(acc[bb], off, 64);
    }
    if (lane == 0) {
      float vbv = vb[(size_t)m * EMBn + hh * HSn + rr];
#pragma unroll
      for (int bb = 0; bb < Bn; ++bb) {
        out[(((size_t)bb * Hn + hh) * Mn + m) * HSn + rr] =
            acc[bb] * sInv[bb] + vbv;
      }
    }
  }
}

extern "C" void kernel_launch(void* const* d_in, const int* in_sizes, int n_in,
                              void* d_out, int out_size, void* d_ws,
                              size_t ws_size, hipStream_t stream) {
  const float* x = (const float*)d_in[0];
  const float* cells = (const float*)d_in[1];
  const float* q_w = (const float*)d_in[2];
  const float* q_b = (const float*)d_in[3];
  const float* v = (const float*)d_in[4];
  const float* vbp = (const float*)d_in[5];
  const float* ln_g = (const float*)d_in[6];
  const float* ln_b = (const float*)d_in[7];
  float* out = (float*)d_out;

  u16* hb = (u16*)d_ws;                            // 2 MB
  u16* htb = hb + (size_t)Bn * Ln * EMBn;          // 2 MB
  u16* Pb = htb + (size_t)Bn * Ln * EMBn;          // 256 KB
  u16* Eb = Pb + (size_t)Rn * EMBn;                // 1 MB
  float* pb = (float*)(Eb + (size_t)Bn * Rn * Ln); // 1 KB
  float* spart = pb + Rn;                          // 4*256*32 f32 = 128 KB
  float* G = spart + (size_t)Bn * Rn * 32;         // 2 MB

  ln_pproj_kernel<<<768, 256, 0, stream>>>(x, ln_g, ln_b, cells, q_w, q_b, hb,
                                           Pb, pb);
  escore_trans_kernel<<<768, 256, 0, stream>>>(hb, Pb, pb, Eb, spart, htb);
  gmat_kernel<<<512, 256, 0, stream>>>(Eb, htb, G);
  out_kernel<<<2048, 256, 0, stream>>>(v, vbp, G, spart, out);
}